// Round 5
// baseline (273.039 us; speedup 1.0000x reference)
//
#include <hip/hip_runtime.h>
#include <math.h>

#define NN 100000
#define NE 1600000
#define D 64
#define NQ (NE / 4)

#define NBD 196                     // dst buckets, width 512 (dst>>9)
#define NBS 391                     // src buckets, width 256 (src>>8)

#define KB 125                      // partition blocks
#define QPB (NQ / KB)               // 3200 int4 quads per block (exact)
#define CAPB 128                    // D-cell capacity, ints   (lambda 65.3, +7.7 sigma)
#define CAPS_PB 80                  // S-cell capacity, bytes  (lambda 32.7, +8.3 sigma)
#define PTB 512
#define TFB (NN / 32)               // 3125 transform blocks (4 nodes/wave, 8 waves)

typedef _Float16 h4v __attribute__((ext_vector_type(4)));
typedef _Float16 h8v __attribute__((ext_vector_type(8)));

// ---------------- K1 (fused): blocks [0,KB) partition | [KB,KB+TFB) transform1 --------
// DETERMINISTIC-SLOT partition: slab cell for (bucket i, block b) starts at the fixed
// base (i*KB+b)*CAP. No global cursor reservation -> the 587-address, KB-deep
// device-scope RMW chains (measured ~37us tail, invariant to waves/CU, scaling with KB
// over r0/r2/r4) are gone, and the counting pass is deleted (count = cursor - base).
// Transform1: t_h = fp16(x @ W1) — NO nsrc (applied per-edge in aggregate-1).
__global__ __launch_bounds__(PTB) void partition_tf1_kernel(
    const int* __restrict__ src, const int* __restrict__ dst,
    int* __restrict__ cntD, int* __restrict__ cntS,
    int* __restrict__ pbuf, unsigned char* __restrict__ qloc,
    const float* __restrict__ x, const float* __restrict__ W1,
    _Float16* __restrict__ t_h)
{
    int t = threadIdx.x, b = blockIdx.x;
    if (b >= KB) {
        // ---- transform1 ----
        __shared__ float Wlds[D * D];
        for (int i = t; i < D * D; i += PTB) Wlds[i] = W1[i];
        __syncthreads();
        int wave = ((b - KB) * PTB + t) >> 6;
        int lane = t & 63;
        int g = lane >> 4, c = lane & 15;
        int node = wave * 4 + g;                    // wave*4 < NN guaranteed (TFB exact)
        float4 xv = *(const float4*)(x + (size_t)node * D + (c << 2));
        float4 acc = {0.f, 0.f, 0.f, 0.f};
#pragma unroll
        for (int k = 0; k < D; ++k) {
            int srcl = (g << 4) | (k >> 2);
            float comp = ((k & 3) == 0) ? xv.x : ((k & 3) == 1) ? xv.y
                       : ((k & 3) == 2) ? xv.z : xv.w;
            float xk = __shfl(comp, srcl, 64);
            float4 w4 = *(const float4*)(Wlds + k * D + (c << 2));
            acc.x += xk * w4.x; acc.y += xk * w4.y;
            acc.z += xk * w4.z; acc.w += xk * w4.w;
        }
        h4v o;
        o[0] = (_Float16)acc.x; o[1] = (_Float16)acc.y;
        o[2] = (_Float16)acc.z; o[3] = (_Float16)acc.w;
        *(h4v*)(t_h + (size_t)node * D + (c << 2)) = o;
        return;
    }
    // ---- partition: single pass, LDS cursors from deterministic bases ----
    __shared__ int hD[NBD], hS[NBS];
    for (int i = t; i < NBD; i += PTB) hD[i] = (i * KB + b) * CAPB;
    for (int i = t; i < NBS; i += PTB) hS[i] = (i * KB + b) * CAPS_PB;
    __syncthreads();
    const int4* s4 = (const int4*)src + (size_t)b * QPB;
    const int4* d4 = (const int4*)dst + (size_t)b * QPB;
    for (int i = t; i < QPB; i += PTB) {
        int4 a = s4[i], d = d4[i];
        int p;
        p = atomicAdd(&hD[d.x >> 9], 1); pbuf[p] = ((d.x & 511) << 17) | a.x;
        p = atomicAdd(&hD[d.y >> 9], 1); pbuf[p] = ((d.y & 511) << 17) | a.y;
        p = atomicAdd(&hD[d.z >> 9], 1); pbuf[p] = ((d.z & 511) << 17) | a.z;
        p = atomicAdd(&hD[d.w >> 9], 1); pbuf[p] = ((d.w & 511) << 17) | a.w;
        p = atomicAdd(&hS[a.x >> 8], 1); qloc[p] = (unsigned char)(a.x & 255);
        p = atomicAdd(&hS[a.y >> 8], 1); qloc[p] = (unsigned char)(a.y & 255);
        p = atomicAdd(&hS[a.z >> 8], 1); qloc[p] = (unsigned char)(a.z & 255);
        p = atomicAdd(&hS[a.w >> 8], 1); qloc[p] = (unsigned char)(a.w & 255);
    }
    __syncthreads();
    for (int i = t; i < NBD; i += PTB) cntD[i * KB + b] = hD[i] - (i * KB + b) * CAPB;
    for (int i = t; i < NBS; i += PTB) cntS[i * KB + b] = hS[i] - (i * KB + b) * CAPS_PB;
}

// ---------------- K2: scan — bucket totals + exclusive prefix -> rowbase ----------
__global__ __launch_bounds__(256) void scan_kernel(const int* __restrict__ cntD,
                                                   int* __restrict__ rowbase,
                                                   int* __restrict__ row_ptr) {
    __shared__ int tot[256];
    int t = threadIdx.x;
    int s = 0;
    if (t < NBD) {
        const int* p = cntD + t * KB;
        for (int b = 0; b < KB; ++b) s += p[b];
    }
    tot[t] = s;
    __syncthreads();
    if (t < 64) {
        int v[4];
        int sum = 0;
#pragma unroll
        for (int j = 0; j < 4; ++j) { v[j] = tot[t * 4 + j]; sum += v[j]; }
        int incl = sum;
        for (int o = 1; o < 64; o <<= 1) {
            int u = __shfl_up(incl, o, 64);
            if (t >= o) incl += u;
        }
        int run = incl - sum;
#pragma unroll
        for (int j = 0; j < 4; ++j) { rowbase[t * 4 + j] = run; run += v[j]; }
    }
    if (t == 255) row_ptr[NN] = NE;
}

// ---------------- K3: finalize (ragged per-cell runs; run length wave-uniform) -------
__global__ __launch_bounds__(PTB) void finalize_kernel(
    const int* __restrict__ pbuf, const unsigned char* __restrict__ qloc,
    const int* __restrict__ cntD, const int* __restrict__ cntS,
    const int* __restrict__ rowbase,
    int* __restrict__ row_ptr, float* __restrict__ nsrc,
    float* __restrict__ ndst, int* __restrict__ esrc)
{
    int B = blockIdx.x, t = threadIdx.x;
    int lane = t & 63, w = t >> 6;
    if (B >= NBD) {
        int q = B - NBD;
        __shared__ int h[256];
        __shared__ int cs[KB];
        if (t < 256) h[t] = 0;
        if (t < KB) cs[t] = cntS[q * KB + t];
        __syncthreads();
        for (int r = w; r < KB; r += 8) {
            int c = cs[r];
            const unsigned char* run = qloc + ((size_t)q * KB + r) * CAPS_PB;
            for (int k = lane; k < c; k += 64) atomicAdd(&h[run[k]], 1);
        }
        __syncthreads();
        if (t < 256) {
            int n = (q << 8) + t;
            if (n < NN) nsrc[n] = 1.0f / sqrtf(fmaxf((float)h[t], 1.0f));
        }
        return;
    }
    __shared__ int fh[512], fcur[512];
    __shared__ int cl[KB];
    if (t < KB) cl[t] = cntD[B * KB + t];
    for (int i = t; i < 512; i += PTB) fh[i] = 0;
    __syncthreads();
    int beg = rowbase[B];
    for (int r = w; r < KB; r += 8) {
        int c = cl[r];
        const int* run = pbuf + ((size_t)B * KB + r) * CAPB;
        for (int k = lane; k < c; k += 64) atomicAdd(&fh[run[k] >> 17], 1);
    }
    __syncthreads();
    if (w == 0) {
        int v[8];
        int s = 0;
#pragma unroll
        for (int j = 0; j < 8; ++j) { v[j] = fh[lane * 8 + j]; s += v[j]; }
        int incl = s;
        for (int o = 1; o < 64; o <<= 1) {
            int u = __shfl_up(incl, o, 64);
            if (lane >= o) incl += u;
        }
        int run = incl - s;
#pragma unroll
        for (int j = 0; j < 8; ++j) {
            int bin = lane * 8 + j;
            fcur[bin] = run;
            int n = (B << 9) + bin;
            if (n < NN) {
                row_ptr[n] = beg + run;
                ndst[n] = 1.0f / sqrtf(fmaxf((float)v[j], 1.0f));
            }
            run += v[j];
        }
    }
    __syncthreads();
    for (int r = w; r < KB; r += 8) {
        int c = cl[r];
        const int* run = pbuf + ((size_t)B * KB + r) * CAPB;
        for (int k = lane; k < c; k += 64) {
            int v = run[k];
            int p = atomicAdd(&fcur[v >> 17], 1);
            esrc[beg + p] = v & 0x1FFFF;
        }
    }
}

// ---------------- dense transform (layer 2): t[v] = fp16( nsrc[v] * (xin[v] @ W) ) ------
__global__ __launch_bounds__(256) void transform_kernel(const float* __restrict__ xin,
                                                        const float* __restrict__ W,
                                                        const float* __restrict__ nsrc,
                                                        _Float16* __restrict__ out) {
    __shared__ float Wlds[D * D];
    for (int i = threadIdx.x; i < D * D; i += 256) Wlds[i] = W[i];
    __syncthreads();
    int wave = (blockIdx.x * 256 + threadIdx.x) >> 6;
    int lane = threadIdx.x & 63;
    int g = lane >> 4, c = lane & 15;
    int node0 = wave * 4;
    if (node0 >= NN) return;
    int node = node0 + g;
    float4 xv = *(const float4*)(xin + (size_t)node * D + (c << 2));
    float4 acc = {0.f, 0.f, 0.f, 0.f};
#pragma unroll
    for (int k = 0; k < D; ++k) {
        int srcl = (g << 4) | (k >> 2);
        float comp = ((k & 3) == 0) ? xv.x : ((k & 3) == 1) ? xv.y
                   : ((k & 3) == 2) ? xv.z : xv.w;
        float xk = __shfl(comp, srcl, 64);
        float4 w4 = *(const float4*)(Wlds + k * D + (c << 2));
        acc.x += xk * w4.x; acc.y += xk * w4.y;
        acc.z += xk * w4.z; acc.w += xk * w4.w;
    }
    float sc = nsrc[node];
    h4v o;
    o[0] = (_Float16)(acc.x * sc); o[1] = (_Float16)(acc.y * sc);
    o[2] = (_Float16)(acc.z * sc); o[3] = (_Float16)(acc.w * sc);
    *(h4v*)(out + (size_t)node * D + (c << 2)) = o;
}

// ---------------- aggregation (fp16 gather, fp32 accumulate; proven) ----------------
template<int RELU, int USE_NSRC>
__global__ __launch_bounds__(256) void aggregate_kernel(const _Float16* __restrict__ t,
                                                        const int* __restrict__ row_ptr,
                                                        const int* __restrict__ esrc,
                                                        const float* __restrict__ nsrc,
                                                        const float* __restrict__ ndst,
                                                        const float* __restrict__ bias,
                                                        float* __restrict__ out) {
    int node = (blockIdx.x * 256 + threadIdx.x) >> 6;
    int lane = threadIdx.x & 63;
    int g = lane >> 3, c = lane & 7;
    if (node >= NN) return;
    int beg = row_ptr[node], end = row_ptr[node + 1];
    float a0[8] = {0,0,0,0,0,0,0,0};
    float a1[8] = {0,0,0,0,0,0,0,0};
    int i = beg;
    for (; i + 16 <= end; i += 16) {
        int s0 = esrc[i + g];
        int s1 = esrc[i + 8 + g];
        float ns0 = USE_NSRC ? nsrc[s0] : 1.0f;
        float ns1 = USE_NSRC ? nsrc[s1] : 1.0f;
        h8v v0 = *(const h8v*)(t + (size_t)s0 * D + (c << 3));
        h8v v1 = *(const h8v*)(t + (size_t)s1 * D + (c << 3));
#pragma unroll
        for (int j = 0; j < 8; ++j) {
            if (USE_NSRC) { a0[j] += (float)v0[j] * ns0; a1[j] += (float)v1[j] * ns1; }
            else          { a0[j] += (float)v0[j];       a1[j] += (float)v1[j]; }
        }
    }
    for (; i < end; i += 8) {
        int e = i + g;
        if (e < end) {
            int s = esrc[e];
            float ns = USE_NSRC ? nsrc[s] : 1.0f;
            h8v v = *(const h8v*)(t + (size_t)s * D + (c << 3));
#pragma unroll
            for (int j = 0; j < 8; ++j) {
                if (USE_NSRC) a0[j] += (float)v[j] * ns;
                else          a0[j] += (float)v[j];
            }
        }
    }
#pragma unroll
    for (int j = 0; j < 8; ++j) a0[j] += a1[j];
#pragma unroll
    for (int j = 0; j < 8; ++j) {
        a0[j] += __shfl_xor(a0[j], 8, 64);
        a0[j] += __shfl_xor(a0[j], 16, 64);
        a0[j] += __shfl_xor(a0[j], 32, 64);
    }
    float nd = ndst[node];
    float4 blo = *(const float4*)(bias + (c << 3));
    float4 bhi = *(const float4*)(bias + (c << 3) + 4);
    float h[8];
    h[0] = a0[0] * nd + blo.x; h[1] = a0[1] * nd + blo.y;
    h[2] = a0[2] * nd + blo.z; h[3] = a0[3] * nd + blo.w;
    h[4] = a0[4] * nd + bhi.x; h[5] = a0[5] * nd + bhi.y;
    h[6] = a0[6] * nd + bhi.z; h[7] = a0[7] * nd + bhi.w;
    if (RELU) {
#pragma unroll
        for (int j = 0; j < 8; ++j) h[j] = fmaxf(h[j], 0.f);
    }
    if (g == 0) {
        float4 o0 = {h[0], h[1], h[2], h[3]};
        float4 o1 = {h[4], h[5], h[6], h[7]};
        *(float4*)(out + (size_t)node * D + (c << 3)) = o0;
        *(float4*)(out + (size_t)node * D + (c << 3) + 4) = o1;
    }
}

// ---------------- launcher ----------------
extern "C" void kernel_launch(void* const* d_in, const int* in_sizes, int n_in,
                              void* d_out, int out_size, void* d_ws, size_t ws_size,
                              hipStream_t stream) {
    const float* x  = (const float*)d_in[0];
    const int* src  = (const int*)d_in[1];
    const int* dst  = (const int*)d_in[2];
    const float* W1 = (const float*)d_in[3];
    const float* b1 = (const float*)d_in[4];
    const float* W2 = (const float*)d_in[5];
    const float* b2 = (const float*)d_in[6];
    float* out = (float*)d_out;

    size_t off = 0;
    auto alloc = [&](size_t bytes) -> void* {
        void* p = (char*)d_ws + off;
        off += (bytes + 255) & ~(size_t)255;
        return p;
    };
    int* row_ptr  = (int*)alloc((size_t)(NN + 1) * 4);
    float* nsrc   = (float*)alloc((size_t)NN * 4);
    float* ndst   = (float*)alloc((size_t)NN * 4);
    int* rowbase  = (int*)alloc((size_t)256 * 4);
    int* cntD     = (int*)alloc((size_t)NBD * KB * 4);           // 98 KB
    int* cntS     = (int*)alloc((size_t)NBS * KB * 4);           // 196 KB
    int* esrc     = (int*)alloc((size_t)NE * 4);                 // 6.4 MB
    _Float16* t_h = (_Float16*)alloc((size_t)NN * D * 2);        // 12.8 MB
    float* h1     = (float*)alloc((size_t)NN * D * 4);           // 25.6 MB
    (void)ws_size;

    // prep scratch aliases h1 (dead until aggregate1 writes it):
    // pbuf 196*125*128*4 = 12.54MB | qloc 391*125*80 = 3.91MB -> 16.5MB < 25.6MB
    int* pbuf = (int*)h1;
    unsigned char* qloc = (unsigned char*)(pbuf + (size_t)NBD * KB * CAPB);

    partition_tf1_kernel<<<KB + TFB, PTB, 0, stream>>>(src, dst, cntD, cntS,
                                                       pbuf, qloc, x, W1, t_h);
    scan_kernel<<<1, 256, 0, stream>>>(cntD, rowbase, row_ptr);
    finalize_kernel<<<NBD + NBS, PTB, 0, stream>>>(pbuf, qloc, cntD, cntS, rowbase,
                                                   row_ptr, nsrc, ndst, esrc);

    int ag_blocks = NN / 4;
    aggregate_kernel<1, 1><<<ag_blocks, 256, 0, stream>>>(t_h, row_ptr, esrc, nsrc, ndst, b1, h1);
    transform_kernel<<<NN / 16, 256, 0, stream>>>(h1, W2, nsrc, t_h);
    aggregate_kernel<0, 0><<<ag_blocks, 256, 0, stream>>>(t_h, row_ptr, esrc, nsrc, ndst, b2, out);
}